// Round 6
// baseline (102.612 us; speedup 1.0000x reference)
//
#include <hip/hip_runtime.h>

// CLUB loss, algebraically collapsed (O(N*d), x read once):
//   out = -0.5/N * P + 0.5/N^2 * ( <Sx2,Sinv> - 2<Sx,Smuinv> + N*Smu2inv )
// Sinv[d]=sum_i e^{-lv}, Smuinv[d]=sum_i mu e^{-lv}, Sx[d]=sum_j x, Sx2[d]=sum_j x^2
// P = sum (x-mu)^2 e^{-lv},  Smu2inv = sum mu^2 e^{-lv}
//
// R6: ONE fused persistent kernel (392 blocks x 256 thr), block = (b, 16-hw tile),
// both 256-col halves with cross-half prefetch; last-block-done reduction
// (device-scope counter + __hip_atomic_load) replaces the fin dispatch.
// 2 dispatches total (4B-scale memset + kernel) vs R5's 3 + 512KB memset.

#define Dd   512
#define HWs  784
#define Nn   6272
#define LSx  260      // LDS x-tile stride: %4==0 (b128), %32==4 -> 2-way only (free)
#define NBLK 392

// ws float offsets: Inv rep*512+c | Mu 4096+ | Sx 8192+ | Sx2 12288+  (rep<8)
// doubles @byte 65536: P[8], M2[8].  uint counter @byte 65664.

__global__ __launch_bounds__(256) void club_all(
    const float* __restrict__ x, const float* __restrict__ p_mu,
    const float* __restrict__ p_lv, float* __restrict__ ws,
    float* __restrict__ out)
{
    __shared__ __align__(16) float smem[2 * 16 * LSx];
    __shared__ float sbuf[16];
    __shared__ int lastFlag;

    const int t   = threadIdx.x;
    const int j   = blockIdx.x;          // 0..391
    const int b   = j / 49;
    const int ht  = j % 49;
    const int hw0 = ht * 16;
    const int r0  = b * HWs + hw0;
    const int rep = j & 7;

    // ---- issue x loads for BOTH halves (8 dwordx4 in flight) ----
    const int dx = t >> 2, g = t & 3;
    const float* xb0 = x + ((size_t)(b * Dd + dx) * HWs + hw0 + 4 * g);
    const float4 A0 = *(const float4*)(xb0);
    const float4 A1 = *(const float4*)(xb0 +  64 * HWs);
    const float4 A2 = *(const float4*)(xb0 + 128 * HWs);
    const float4 A3 = *(const float4*)(xb0 + 192 * HWs);
    const float* xb1 = xb0 + 256 * HWs;
    const float4 B0 = *(const float4*)(xb1);
    const float4 B1 = *(const float4*)(xb1 +  64 * HWs);
    const float4 B2 = *(const float4*)(xb1 + 128 * HWs);
    const float4 B3 = *(const float4*)(xb1 + 192 * HWs);

    // ---- mu/lv half0 (8 more dwordx4 in flight) ----
    const size_t mb0 = (size_t)(r0 + (t >> 6)) * Dd + 4 * (t & 63);
    const float4 M00 = *(const float4*)(p_mu + mb0);
    const float4 M01 = *(const float4*)(p_mu + mb0 + 2048);
    const float4 M02 = *(const float4*)(p_mu + mb0 + 4096);
    const float4 M03 = *(const float4*)(p_mu + mb0 + 6144);
    const float4 L00 = *(const float4*)(p_lv + mb0);
    const float4 L01 = *(const float4*)(p_lv + mb0 + 2048);
    const float4 L02 = *(const float4*)(p_lv + mb0 + 4096);
    const float4 L03 = *(const float4*)(p_lv + mb0 + 6144);

    // ---- transpose both x halves into LDS: smem[half*16*LSx + row*LSx + col] ----
#define XST(V, HALF, K) do {                                           \
        const int c_ = dx + 64 * (K);                                  \
        float* s_ = smem + (HALF) * 16 * LSx + (4 * g) * LSx + c_;     \
        s_[0 * LSx] = (V).x; s_[1 * LSx] = (V).y;                      \
        s_[2 * LSx] = (V).z; s_[3 * LSx] = (V).w;                      \
    } while (0)
    XST(A0, 0, 0); XST(A1, 0, 1); XST(A2, 0, 2); XST(A3, 0, 3);
    XST(B0, 1, 0); XST(B1, 1, 1); XST(B2, 1, 2); XST(B3, 1, 3);
#undef XST

    // ---- mu/lv half1 issued before compute h0 (overlap) ----
    const size_t mb1 = mb0 + 256;
    const float4 M10 = *(const float4*)(p_mu + mb1);
    const float4 M11 = *(const float4*)(p_mu + mb1 + 2048);
    const float4 M12 = *(const float4*)(p_mu + mb1 + 4096);
    const float4 M13 = *(const float4*)(p_mu + mb1 + 6144);
    const float4 L10 = *(const float4*)(p_lv + mb1);
    const float4 L11 = *(const float4*)(p_lv + mb1 + 2048);
    const float4 L12 = *(const float4*)(p_lv + mb1 + 4096);
    const float4 L13 = *(const float4*)(p_lv + mb1 + 6144);

    __syncthreads();   // transposes visible

    const int cc = 4 * (t & 63);
    const int rb = t >> 6;
    float4 aI0 = {0,0,0,0}, aM0 = {0,0,0,0}, sX0 = {0,0,0,0}, s20 = {0,0,0,0};
    float4 aI1 = {0,0,0,0}, aM1 = {0,0,0,0}, sX1 = {0,0,0,0}, s21 = {0,0,0,0};
    float aP = 0.f, aM2 = 0.f;

#define ACC1(XV, MU, LV, F, AI, AM, SX, S2) do {                       \
        const float iev = __expf(-(LV).F);                             \
        const float dd  = (XV).F - (MU).F;                             \
        aP += dd * dd * iev;                                           \
        (AI).F += iev;                                                 \
        const float mi = (MU).F * iev;                                 \
        (AM).F += mi; aM2 += (MU).F * mi;                              \
        (SX).F += (XV).F; (S2).F += (XV).F * (XV).F;                   \
    } while (0)
#define ACCROW(HALF, K, MU, LV, AI, AM, SX, S2) do {                   \
        const float4 xv = *(const float4*)&smem[(HALF)*16*LSx + (rb + 4*(K))*LSx + cc]; \
        ACC1(xv, MU, LV, x, AI, AM, SX, S2);                           \
        ACC1(xv, MU, LV, y, AI, AM, SX, S2);                           \
        ACC1(xv, MU, LV, z, AI, AM, SX, S2);                           \
        ACC1(xv, MU, LV, w, AI, AM, SX, S2);                           \
    } while (0)
    ACCROW(0, 0, M00, L00, aI0, aM0, sX0, s20);
    ACCROW(0, 1, M01, L01, aI0, aM0, sX0, s20);
    ACCROW(0, 2, M02, L02, aI0, aM0, sX0, s20);
    ACCROW(0, 3, M03, L03, aI0, aM0, sX0, s20);
    ACCROW(1, 0, M10, L10, aI1, aM1, sX1, s21);
    ACCROW(1, 1, M11, L11, aI1, aM1, sX1, s21);
    ACCROW(1, 2, M12, L12, aI1, aM1, sX1, s21);
    ACCROW(1, 3, M13, L13, aI1, aM1, sX1, s21);
#undef ACCROW
#undef ACC1

    // ---- per-column LDS reduces (t, t+64, t+128, t+192 share cols) ----
    float4* red4 = (float4*)smem;
    float4 rI0, rM0, rX0, r20, rI1, rM1, rX1, r21;
#define COLRED(SRC, DST) do {                                          \
        __syncthreads();                                               \
        red4[t] = (SRC);                                               \
        __syncthreads();                                               \
        if (t < 128) { float4 o = red4[t + 128];                       \
            red4[t].x += o.x; red4[t].y += o.y;                        \
            red4[t].z += o.z; red4[t].w += o.w; }                      \
        __syncthreads();                                               \
        if (t < 64) { float4 a = red4[t], o = red4[t + 64];            \
            (DST).x = a.x + o.x; (DST).y = a.y + o.y;                  \
            (DST).z = a.z + o.z; (DST).w = a.w + o.w; }                \
    } while (0)
    COLRED(aI0, rI0); COLRED(aM0, rM0); COLRED(sX0, rX0); COLRED(s20, r20);
    COLRED(aI1, rI1); COLRED(aM1, rM1); COLRED(sX1, rX1); COLRED(s21, r21);
#undef COLRED

    // ---- scalar wave reduce, park in LDS (barriers BEFORE atomics) ----
#pragma unroll
    for (int off = 32; off > 0; off >>= 1) {
        aP  += __shfl_down(aP,  off);
        aM2 += __shfl_down(aM2, off);
    }
    __syncthreads();
    if ((t & 63) == 0) { sbuf[t >> 6] = aP; sbuf[8 + (t >> 6)] = aM2; }
    __syncthreads();

    // ---- fire-and-forget atomics to 8 replicas ----
    if (t < 64) {
#define ATOM4(OFF, C, V) do {                                          \
        float* p_ = ws + (OFF) + rep * Dd + (C);                       \
        atomicAdd(p_ + 0, (V).x); atomicAdd(p_ + 1, (V).y);            \
        atomicAdd(p_ + 2, (V).z); atomicAdd(p_ + 3, (V).w);            \
    } while (0)
        ATOM4(0,     4 * t,       rI0); ATOM4(0,     256 + 4 * t, rI1);
        ATOM4(4096,  4 * t,       rM0); ATOM4(4096,  256 + 4 * t, rM1);
        ATOM4(8192,  4 * t,       rX0); ATOM4(8192,  256 + 4 * t, rX1);
        ATOM4(12288, 4 * t,       r20); ATOM4(12288, 256 + 4 * t, r21);
#undef ATOM4
    }
    if (t == 0) {
        double* wd = (double*)((char*)ws + 65536);
        atomicAdd(wd + rep,     (double)(sbuf[0] + sbuf[1] + sbuf[2] + sbuf[3]));
        atomicAdd(wd + 8 + rep, (double)(sbuf[8] + sbuf[9] + sbuf[10] + sbuf[11]));
    }

    // ---- last-block-done reduction ----
    if (t == 0) {
        __threadfence();   // release our atomics before the counter bump
        unsigned* ctr = (unsigned*)((char*)ws + 65664);
        lastFlag = (atomicAdd(ctr, 1u) == NBLK - 1);
    }
    __syncthreads();
    if (!lastFlag) return;

    __threadfence();       // acquire: everyone's atomics precede our counter view
    double* redd = (double*)smem;
    double dc = 0.0;
#pragma unroll
    for (int half = 0; half < 2; ++half) {
        const int c = t + 256 * half;
        double sI = 0.0, sM = 0.0, sX = 0.0, s2 = 0.0;
#pragma unroll
        for (int r = 0; r < 8; ++r) {
            sI += (double)__hip_atomic_load(ws +         r * Dd + c, __ATOMIC_RELAXED, __HIP_MEMORY_SCOPE_AGENT);
            sM += (double)__hip_atomic_load(ws +  4096 + r * Dd + c, __ATOMIC_RELAXED, __HIP_MEMORY_SCOPE_AGENT);
            sX += (double)__hip_atomic_load(ws +  8192 + r * Dd + c, __ATOMIC_RELAXED, __HIP_MEMORY_SCOPE_AGENT);
            s2 += (double)__hip_atomic_load(ws + 12288 + r * Dd + c, __ATOMIC_RELAXED, __HIP_MEMORY_SCOPE_AGENT);
        }
        dc += s2 * sI - 2.0 * sX * sM;
    }
    redd[t] = dc; __syncthreads();
    for (int s = 128; s > 0; s >>= 1) {
        if (t < s) redd[t] += redd[t + s];
        __syncthreads();
    }
    if (t == 0) {
        double* wd = (double*)((char*)ws + 65536);
        double P = 0.0, M2 = 0.0;
#pragma unroll
        for (int r = 0; r < 8; ++r) {
            P  += __hip_atomic_load(wd + r,     __ATOMIC_RELAXED, __HIP_MEMORY_SCOPE_AGENT);
            M2 += __hip_atomic_load(wd + 8 + r, __ATOMIC_RELAXED, __HIP_MEMORY_SCOPE_AGENT);
        }
        const double sumD = redd[0] + (double)Nn * M2;
        out[0] = (float)((-0.5 / (double)Nn) * P
                       + (0.5 / ((double)Nn * (double)Nn)) * sumD);
    }
}

extern "C" void kernel_launch(void* const* d_in, const int* in_sizes, int n_in,
                              void* d_out, int out_size, void* d_ws, size_t ws_size,
                              hipStream_t stream) {
    const float* x    = (const float*)d_in[0];
    const float* p_mu = (const float*)d_in[1];
    const float* p_lv = (const float*)d_in[2];
    float* ws = (float*)d_ws;

    // zero: 64KB float accumulators + 16 doubles + counter
    hipMemsetAsync(d_ws, 0, 65668, stream);
    club_all<<<NBLK, 256, 0, stream>>>(x, p_mu, p_lv, ws, (float*)d_out);
}